// Round 5
// baseline (1250.033 us; speedup 1.0000x reference)
//
#include <hip/hip_runtime.h>

#define N_RID  100000
#define N_CELL 400000
#define NCOLS  4
#define NE     100000
#define D      64
#define TOTE   (NCOLS * NE)          // 400000 edges per direction
#define GST    68                    // gbuf row stride (floats): 16B-aligned, bank-spread

typedef __attribute__((ext_vector_type(8))) short bf16x8;
typedef __attribute__((ext_vector_type(4))) float f32x4;

__device__ inline unsigned short f2bf(float f) {
    unsigned int u = __float_as_uint(f);
    return (unsigned short)((u + 0x7FFF + ((u >> 16) & 1)) >> 16);
}
__device__ inline float bf2f(unsigned short b) {
    return __uint_as_float(((unsigned int)b) << 16);
}
__device__ inline unsigned long long pack4(unsigned short a, unsigned short b,
                                           unsigned short c, unsigned short d) {
    return (unsigned long long)a | ((unsigned long long)b << 16) |
           ((unsigned long long)c << 32) | ((unsigned long long)d << 48);
}
// byte offset within a [16 rows][128B] bf16 tile, XOR-swizzled (bank-conflict fix)
__device__ inline int swz(int row, int kbyte) {
    return row * 128 + (kbyte ^ ((row & 7) << 4));
}

// ================================================================ CSR build
__global__ void hist_kernel(const int* __restrict__ dst, int* __restrict__ cnt,
                            int ndst) {
    int t = blockIdx.x * 256 + threadIdx.x;
    if (t >= TOTE) return;
    int c = t / NE;
    atomicAdd(&cnt[c * ndst + dst[t]], 1);
}

__global__ void scan1(const int* __restrict__ in, int* __restrict__ out,
                      int* __restrict__ csum, int n) {
    __shared__ int lds[256];
    int base = blockIdx.x * 1024 + threadIdx.x * 4;
    int v0 = 0, v1 = 0, v2 = 0, v3 = 0;
    if (base + 0 < n) v0 = in[base + 0];
    if (base + 1 < n) v1 = in[base + 1];
    if (base + 2 < n) v2 = in[base + 2];
    if (base + 3 < n) v3 = in[base + 3];
    int tsum = v0 + v1 + v2 + v3;
    lds[threadIdx.x] = tsum;
    __syncthreads();
    for (int off = 1; off < 256; off <<= 1) {
        int x = (threadIdx.x >= off) ? lds[threadIdx.x - off] : 0;
        __syncthreads();
        lds[threadIdx.x] += x;
        __syncthreads();
    }
    int excl = lds[threadIdx.x] - tsum;
    if (base + 0 < n) out[base + 0] = excl;
    if (base + 1 < n) out[base + 1] = excl + v0;
    if (base + 2 < n) out[base + 2] = excl + v0 + v1;
    if (base + 3 < n) out[base + 3] = excl + v0 + v1 + v2;
    if (threadIdx.x == 255) csum[blockIdx.x] = lds[255];
}

__global__ void scan2(int* __restrict__ a, int m) {
    __shared__ int lds[256];
    int per = (m + 255) >> 8;
    int st = threadIdx.x * per;
    int s = 0;
    for (int i = 0; i < per; ++i) if (st + i < m) s += a[st + i];
    lds[threadIdx.x] = s;
    __syncthreads();
    for (int off = 1; off < 256; off <<= 1) {
        int x = (threadIdx.x >= off) ? lds[threadIdx.x - off] : 0;
        __syncthreads();
        lds[threadIdx.x] += x;
        __syncthreads();
    }
    int run = lds[threadIdx.x] - s;
    for (int i = 0; i < per; ++i) if (st + i < m) { int v = a[st + i]; a[st + i] = run; run += v; }
}

__global__ void scan3(int* __restrict__ out, const int* __restrict__ csum, int n) {
    int i = blockIdx.x * 256 + threadIdx.x;
    if (i < n) out[i] += csum[i >> 10];
}

__global__ void set_sentinels(int* __restrict__ pF, int* __restrict__ pR) {
    if (threadIdx.x == 0) {
        pF[NCOLS * N_CELL] = TOTE;
        pR[NCOLS * N_RID]  = TOTE;
    }
}

// destructive fill; packs local dst row (dst & 15) into col bits [20:24)
__global__ void fill_kernel(const int* __restrict__ dst, const int* __restrict__ src,
                            const int* __restrict__ ptr, int* __restrict__ cnt,
                            int* __restrict__ col, int ndst) {
    int t = blockIdx.x * 256 + threadIdx.x;
    if (t >= TOTE) return;
    int c = t / NE;
    int d = dst[t];
    int bin = c * ndst + d;
    int old = atomicSub(&cnt[bin], 1);
    col[ptr[bin] + old - 1] = src[t] | ((d & 15) << 20);
}

// ---------------- W prep: Wt[c][j][k] = bf16(W[c][k][j]) for 4 weight sets
__global__ void prep_w(const float* __restrict__ Wa, const float* __restrict__ Wb,
                       const float* __restrict__ Wc, const float* __restrict__ Wd,
                       unsigned short* __restrict__ Ta, unsigned short* __restrict__ Tb,
                       unsigned short* __restrict__ Tc, unsigned short* __restrict__ Td) {
    int t = blockIdx.x * 256 + threadIdx.x;
    if (t >= NCOLS * D * D) return;
    int c = t >> 12, jk = t & 4095, j = jk >> 6, k = jk & 63;
    int s = (c * D + k) * D + j;
    Ta[t] = f2bf(Wa[s]);
    Tb[t] = f2bf(Wb[s]);
    Tc[t] = f2bf(Wc[s]);
    Td[t] = f2bf(Wd[s]);
}

// ======================= y = (h - mu) @ W_c (MFMA, 4 relations, 16 rows/block)
__global__ void __launch_bounds__(256) y_gemm(const float* __restrict__ h,
        const unsigned short* __restrict__ Wt, const float* __restrict__ mu,
        float* __restrict__ y, int nrows) {
    __shared__ unsigned short aHi[16 * D], aLo[16 * D];
    __shared__ float part[4][16 * D];
    const int tid = threadIdx.x, c = tid >> 6, l = tid & 63;
    const int row0 = blockIdx.x * 16;

    {   // A tile build: hi/lo split bf16, swizzled
        int r = tid >> 4, c4 = tid & 15;
        float4 v = *(const float4*)(h + (size_t)(row0 + r) * D + c4 * 4);
        if (mu) {
            float4 m = ((const float4*)mu)[c4];
            v.x -= m.x; v.y -= m.y; v.z -= m.z; v.w -= m.w;
        }
        unsigned short h0 = f2bf(v.x), h1 = f2bf(v.y), h2 = f2bf(v.z), h3 = f2bf(v.w);
        unsigned short l0 = f2bf(v.x - bf2f(h0)), l1 = f2bf(v.y - bf2f(h1));
        unsigned short l2 = f2bf(v.z - bf2f(h2)), l3 = f2bf(v.w - bf2f(h3));
        int off = swz(r, c4 * 8);
        *(unsigned long long*)((char*)aHi + off) = pack4(h0, h1, h2, h3);
        *(unsigned long long*)((char*)aLo + off) = pack4(l0, l1, l2, l3);
    }
    __syncthreads();

    bf16x8 bfr[4][2];
#pragma unroll
    for (int nt = 0; nt < 4; ++nt)
#pragma unroll
        for (int kh = 0; kh < 2; ++kh)
            bfr[nt][kh] = *(const bf16x8*)(Wt +
                ((c * D + nt * 16 + (l & 15)) * D + kh * 32 + (l >> 4) * 8));

    bf16x8 ah[2], al[2];
#pragma unroll
    for (int kh = 0; kh < 2; ++kh) {
        int off = swz(l & 15, kh * 64 + (l >> 4) * 16);
        ah[kh] = *(const bf16x8*)((const char*)aHi + off);
        al[kh] = *(const bf16x8*)((const char*)aLo + off);
    }
    f32x4 acc[4] = {};
#pragma unroll
    for (int nt = 0; nt < 4; ++nt) {
        acc[nt] = __builtin_amdgcn_mfma_f32_16x16x32_bf16(ah[0], bfr[nt][0], acc[nt], 0, 0, 0);
        acc[nt] = __builtin_amdgcn_mfma_f32_16x16x32_bf16(ah[1], bfr[nt][1], acc[nt], 0, 0, 0);
        acc[nt] = __builtin_amdgcn_mfma_f32_16x16x32_bf16(al[0], bfr[nt][0], acc[nt], 0, 0, 0);
        acc[nt] = __builtin_amdgcn_mfma_f32_16x16x32_bf16(al[1], bfr[nt][1], acc[nt], 0, 0, 0);
    }
#pragma unroll
    for (int nt = 0; nt < 4; ++nt)
#pragma unroll
        for (int q = 0; q < 4; ++q)
            part[c][((l >> 4) * 4 + q) * D + nt * 16 + (l & 15)] = acc[nt][q];
    __syncthreads();
#pragma unroll
    for (int cc = 0; cc < 4; ++cc) {
        float4 v = ((const float4*)part[cc])[tid];
        *(float4*)(y + ((size_t)cc * nrows + row0) * D + tid * 4) = v;
    }
}

// ====== cell: out[n] = bbar + 0.25*sum_c sc_c(n)*( sum_e y_c[src_e] + (h[n]-mu)@W_c )
__global__ void __launch_bounds__(256) cell_fused(const float* __restrict__ h,
        const float* __restrict__ y, const int* __restrict__ ptr,
        const int* __restrict__ col, const unsigned short* __restrict__ Wt,
        const float* __restrict__ bias, const float* __restrict__ mu,
        float* __restrict__ out) {
    __shared__ unsigned short aHi[16 * D], aLo[16 * D];
    __shared__ float gbuf[4][16 * GST];
    __shared__ int pl[4][17];
    __shared__ float sc[4][16];
    const int tid = threadIdx.x, c = tid >> 6, l = tid & 63;
    const int g = l >> 4, eq = l & 15;
    const int row0 = blockIdx.x * 16;

    if (tid < 4 * 17) {
        int cc = tid / 17, i = tid % 17;
        pl[cc][i] = ptr[(size_t)cc * N_CELL + row0 + i];
    }
    {   // A tile build (1 float4 load per thread)
        int r = tid >> 4, c4 = tid & 15;
        float4 v = *(const float4*)(h + (size_t)(row0 + r) * D + c4 * 4);
        if (mu) {
            float4 m = ((const float4*)mu)[c4];
            v.x -= m.x; v.y -= m.y; v.z -= m.z; v.w -= m.w;
        }
        unsigned short h0 = f2bf(v.x), h1 = f2bf(v.y), h2 = f2bf(v.z), h3 = f2bf(v.w);
        unsigned short l0 = f2bf(v.x - bf2f(h0)), l1 = f2bf(v.y - bf2f(h1));
        unsigned short l2 = f2bf(v.z - bf2f(h2)), l3 = f2bf(v.w - bf2f(h3));
        int off = swz(r, c4 * 8);
        *(unsigned long long*)((char*)aHi + off) = pack4(h0, h1, h2, h3);
        *(unsigned long long*)((char*)aLo + off) = pack4(l0, l1, l2, l3);
    }
    for (int i = tid; i < 4 * 16 * GST; i += 256) ((float*)gbuf)[i] = 0.f;
    __syncthreads();

    if (l < 16) sc[c][l] = 1.0f / (float)(pl[c][l + 1] - pl[c][l] + 1);

    bf16x8 bfr[4][2];
#pragma unroll
    for (int nt = 0; nt < 4; ++nt)
#pragma unroll
        for (int kh = 0; kh < 2; ++kh)
            bfr[nt][kh] = *(const bf16x8*)(Wt +
                ((c * D + nt * 16 + (l & 15)) * D + kh * 32 + (l >> 4) * 8));

    // edge-parallel gather: 4 edges/wave/iter (16 lanes × float4 each), 2-deep pipeline
    {
        const float* ybase = y + (size_t)c * N_RID * D;
        int P0 = pl[c][0], P1 = pl[c][16];
        for (int e0 = P0; e0 < P1; e0 += 8) {
            int eA = e0 + g, eB = e0 + 4 + g;
            int vA = (eA < P1) ? col[eA] : -1;
            int vB = (eB < P1) ? col[eB] : -1;
            float4 yA = {}, yB = {};
            if (vA >= 0) yA = *(const float4*)(ybase + (size_t)(vA & 0xFFFFF) * D + eq * 4);
            if (vB >= 0) yB = *(const float4*)(ybase + (size_t)(vB & 0xFFFFF) * D + eq * 4);
            if (vA >= 0) {
                float* gp = &gbuf[c][(vA >> 20) * GST + eq * 4];
                atomicAdd(gp + 0, yA.x); atomicAdd(gp + 1, yA.y);
                atomicAdd(gp + 2, yA.z); atomicAdd(gp + 3, yA.w);
            }
            if (vB >= 0) {
                float* gp = &gbuf[c][(vB >> 20) * GST + eq * 4];
                atomicAdd(gp + 0, yB.x); atomicAdd(gp + 1, yB.y);
                atomicAdd(gp + 2, yB.z); atomicAdd(gp + 3, yB.w);
            }
        }
    }

    bf16x8 ah[2], al[2];
#pragma unroll
    for (int kh = 0; kh < 2; ++kh) {
        int off = swz(l & 15, kh * 64 + (l >> 4) * 16);
        ah[kh] = *(const bf16x8*)((const char*)aHi + off);
        al[kh] = *(const bf16x8*)((const char*)aLo + off);
    }
    f32x4 acc[4] = {};
#pragma unroll
    for (int nt = 0; nt < 4; ++nt) {
        acc[nt] = __builtin_amdgcn_mfma_f32_16x16x32_bf16(ah[0], bfr[nt][0], acc[nt], 0, 0, 0);
        acc[nt] = __builtin_amdgcn_mfma_f32_16x16x32_bf16(ah[1], bfr[nt][1], acc[nt], 0, 0, 0);
        acc[nt] = __builtin_amdgcn_mfma_f32_16x16x32_bf16(al[0], bfr[nt][0], acc[nt], 0, 0, 0);
        acc[nt] = __builtin_amdgcn_mfma_f32_16x16x32_bf16(al[1], bfr[nt][1], acc[nt], 0, 0, 0);
    }
    // epilogue: in-place RMW (wave-local; same-wave DS ops complete in order)
#pragma unroll
    for (int nt = 0; nt < 4; ++nt)
#pragma unroll
        for (int q = 0; q < 4; ++q) {
            int row = (l >> 4) * 4 + q, cj = nt * 16 + (l & 15);
            float* gp = &gbuf[c][row * GST + cj];
            *gp = sc[c][row] * (acc[nt][q] + *gp);
        }
    __syncthreads();
    for (int i = tid; i < 16 * D; i += 256) {
        int row = i >> 6, j = i & 63;
        float b = 0.25f * (bias[j] + bias[64 + j] + bias[128 + j] + bias[192 + j]);
        out[(size_t)row0 * D + i] =
            0.25f * (gbuf[0][row * GST + j] + gbuf[1][row * GST + j] +
                     gbuf[2][row * GST + j] + gbuf[3][row * GST + j]) + b;
    }
}

// == rid: out[n] = bbar + 0.25*sum_c sc_c(n)*((sum_e hs[src_e] - dg*mu_s + h[n]-mu_d)@W_c)
__global__ void __launch_bounds__(256) rid_fused(const float* __restrict__ h,
        const float* __restrict__ hs, const int* __restrict__ ptr,
        const int* __restrict__ col, const unsigned short* __restrict__ Wt,
        const float* __restrict__ bias, const float* __restrict__ mu_d,
        const float* __restrict__ mu_s, float* __restrict__ out) {
    __shared__ unsigned short aHi4[4][16 * D], aLo4[4][16 * D];
    __shared__ float gbuf[4][16 * GST];
    __shared__ int pl[4][17];
    __shared__ float sc[4][16];
    const int tid = threadIdx.x, c = tid >> 6, l = tid & 63;
    const int g = l >> 4, eq = l & 15;
    const int row0 = blockIdx.x * 16;

    if (tid < 4 * 17) {
        int cc = tid / 17, i = tid % 17;
        pl[cc][i] = ptr[(size_t)cc * N_RID + row0 + i];
    }
    {   // gbuf init = h - mu_d (1 float4 load per thread, fanned to 4 relations)
        int r = tid >> 4, c4 = tid & 15;
        float4 v = *(const float4*)(h + (size_t)(row0 + r) * D + c4 * 4);
        if (mu_d) {
            float4 m = ((const float4*)mu_d)[c4];
            v.x -= m.x; v.y -= m.y; v.z -= m.z; v.w -= m.w;
        }
#pragma unroll
        for (int cc = 0; cc < 4; ++cc)
            *(float4*)(&gbuf[cc][r * GST + c4 * 4]) = v;
    }
    __syncthreads();

    if (l < 16) sc[c][l] = 1.0f / (float)(pl[c][l + 1] - pl[c][l] + 1);
    float muk = mu_s ? mu_s[l] : 0.f;

    bf16x8 bfr[4][2];
#pragma unroll
    for (int nt = 0; nt < 4; ++nt)
#pragma unroll
        for (int kh = 0; kh < 2; ++kh)
            bfr[nt][kh] = *(const bf16x8*)(Wt +
                ((c * D + nt * 16 + (l & 15)) * D + kh * 32 + (l >> 4) * 8));

    // edge-parallel gather of hs rows
    {
        int P0 = pl[c][0], P1 = pl[c][16];
        for (int e0 = P0; e0 < P1; e0 += 8) {
            int eA = e0 + g, eB = e0 + 4 + g;
            int vA = (eA < P1) ? col[eA] : -1;
            int vB = (eB < P1) ? col[eB] : -1;
            float4 yA = {}, yB = {};
            if (vA >= 0) yA = *(const float4*)(hs + (size_t)(vA & 0xFFFFF) * D + eq * 4);
            if (vB >= 0) yB = *(const float4*)(hs + (size_t)(vB & 0xFFFFF) * D + eq * 4);
            if (vA >= 0) {
                float* gp = &gbuf[c][(vA >> 20) * GST + eq * 4];
                atomicAdd(gp + 0, yA.x); atomicAdd(gp + 1, yA.y);
                atomicAdd(gp + 2, yA.z); atomicAdd(gp + 3, yA.w);
            }
            if (vB >= 0) {
                float* gp = &gbuf[c][(vB >> 20) * GST + eq * 4];
                atomicAdd(gp + 0, yB.x); atomicAdd(gp + 1, yB.y);
                atomicAdd(gp + 2, yB.z); atomicAdd(gp + 3, yB.w);
            }
        }
    }

    // A-build from gbuf (wave-local): val = gather + h - mu_d - deg*mu_s
    unsigned short* aHi_c = aHi4[c];
    unsigned short* aLo_c = aLo4[c];
    for (int r = 0; r < 16; ++r) {
        float val = gbuf[c][r * GST + l] - (float)(pl[c][r + 1] - pl[c][r]) * muk;
        unsigned short hi = f2bf(val), lo = f2bf(val - bf2f(hi));
        int off = swz(r, l * 2);
        *(unsigned short*)((char*)aHi_c + off) = hi;
        *(unsigned short*)((char*)aLo_c + off) = lo;
    }

    bf16x8 ah[2], al[2];
#pragma unroll
    for (int kh = 0; kh < 2; ++kh) {
        int off = swz(l & 15, kh * 64 + (l >> 4) * 16);
        ah[kh] = *(const bf16x8*)((const char*)aHi_c + off);
        al[kh] = *(const bf16x8*)((const char*)aLo_c + off);
    }
    f32x4 acc[4] = {};
#pragma unroll
    for (int nt = 0; nt < 4; ++nt) {
        acc[nt] = __builtin_amdgcn_mfma_f32_16x16x32_bf16(ah[0], bfr[nt][0], acc[nt], 0, 0, 0);
        acc[nt] = __builtin_amdgcn_mfma_f32_16x16x32_bf16(ah[1], bfr[nt][1], acc[nt], 0, 0, 0);
        acc[nt] = __builtin_amdgcn_mfma_f32_16x16x32_bf16(al[0], bfr[nt][0], acc[nt], 0, 0, 0);
        acc[nt] = __builtin_amdgcn_mfma_f32_16x16x32_bf16(al[1], bfr[nt][1], acc[nt], 0, 0, 0);
    }
    // part overlay: gbuf dead after A-build (wave-local, program order)
#pragma unroll
    for (int nt = 0; nt < 4; ++nt)
#pragma unroll
        for (int q = 0; q < 4; ++q) {
            int row = (l >> 4) * 4 + q, cj = nt * 16 + (l & 15);
            gbuf[c][row * GST + cj] = sc[c][row] * acc[nt][q];
        }
    __syncthreads();
    for (int i = tid; i < 16 * D; i += 256) {
        int row = i >> 6, j = i & 63;
        float b = 0.25f * (bias[j] + bias[64 + j] + bias[128 + j] + bias[192 + j]);
        out[(size_t)row0 * D + i] =
            0.25f * (gbuf[0][row * GST + j] + gbuf[1][row * GST + j] +
                     gbuf[2][row * GST + j] + gbuf[3][row * GST + j]) + b;
    }
}

// ------------------------- column sums (for centering)
__global__ void colsum(const float* __restrict__ x, float* __restrict__ sum, int nrows) {
    __shared__ float p[4][64];
    int j = threadIdx.x & 63, rl = threadIdx.x >> 6;
    float local = 0.f;
    for (int r = blockIdx.x * 4 + rl; r < nrows; r += gridDim.x * 4)
        local += x[(size_t)r * D + j];
    p[rl][j] = local;
    __syncthreads();
    if (rl == 0) atomicAdd(&sum[j], p[0][j] + p[1][j] + p[2][j] + p[3][j]);
}

__global__ void finalize_mean(float* __restrict__ s, float inv_n) {
    s[threadIdx.x] *= inv_n;
}

__global__ void final_combine(float* __restrict__ out, const float* __restrict__ rid,
        const float* __restrict__ mu_c, const float* __restrict__ mu_r) {
    int t = blockIdx.x * 256 + threadIdx.x;
    if (t >= N_CELL * D) return;
    int row = t >> 6, j = t & 63;
    float v = (row < N_RID) ? (rid[(size_t)row * D + j] - mu_r[j])
                            : (out[t] - mu_c[j]);
    out[t] = fmaxf(v, 0.0f);
}

extern "C" void kernel_launch(void* const* d_in, const int* in_sizes, int n_in,
                              void* d_out, int out_size, void* d_ws, size_t ws_size,
                              hipStream_t stream) {
    const float* x_rid  = (const float*)d_in[0];
    const float* x_cell = (const float*)d_in[1];
    const int* src_fwd  = (const int*)d_in[2];
    const int* dst_fwd  = (const int*)d_in[3];
    const int* src_rev  = (const int*)d_in[4];
    const int* dst_rev  = (const int*)d_in[5];
    const float* W1f = (const float*)d_in[6];
    const float* b1f = (const float*)d_in[7];
    const float* W1r = (const float*)d_in[8];
    const float* b1r = (const float*)d_in[9];
    const float* W2f = (const float*)d_in[10];
    const float* b2f = (const float*)d_in[11];
    const float* W2r = (const float*)d_in[12];
    const float* b2r = (const float*)d_in[13];
    float* out = (float*)d_out;

    float* ws    = (float*)d_ws;
    float* rid1  = ws;
    float* cell1 = rid1  + (size_t)N_RID * D;
    float* rid2  = cell1 + (size_t)N_CELL * D;
    float* y     = rid2  + (size_t)N_RID * D;
    float* sums  = y     + (size_t)NCOLS * N_RID * D;
    int*   ptrF  = (int*)(sums + 256);
    int*   colF  = ptrF + (size_t)NCOLS * N_CELL + 1;
    int*   ptrR  = colF + TOTE;
    int*   colR  = ptrR + (size_t)NCOLS * N_RID + 1;
    uintptr_t wp = ((uintptr_t)(colR + TOTE) + 15) & ~(uintptr_t)15;
    unsigned short* Wt1f = (unsigned short*)wp;
    unsigned short* Wt1r = Wt1f + NCOLS * D * D;
    unsigned short* Wt2f = Wt1r + NCOLS * D * D;
    unsigned short* Wt2r = Wt2f + NCOLS * D * D;
    // build-phase overlays inside rid2 region (dead until layer 2)
    int*   cntF  = (int*)rid2;
    int*   cntR  = cntF + (size_t)NCOLS * N_CELL;
    int*   csumF = cntR + (size_t)NCOLS * N_RID;
    int*   csumR = csumF + 2048;

    const int NBF = NCOLS * N_CELL;
    const int NBR = NCOLS * N_RID;
    const int g_edges = (TOTE + 255) / 256;

    hipMemsetAsync(cntF, 0, (size_t)NBF * sizeof(int), stream);
    hipMemsetAsync(cntR, 0, (size_t)NBR * sizeof(int), stream);
    hipMemsetAsync(sums, 0, 256 * sizeof(float), stream);

    prep_w<<<(NCOLS * D * D + 255) / 256, 256, 0, stream>>>(W1f, W1r, W2f, W2r,
                                                            Wt1f, Wt1r, Wt2f, Wt2r);

    hist_kernel<<<g_edges, 256, 0, stream>>>(dst_fwd, cntF, N_CELL);
    hist_kernel<<<g_edges, 256, 0, stream>>>(dst_rev, cntR, N_RID);
    int nchF = (NBF + 1023) / 1024, nchR = (NBR + 1023) / 1024;
    scan1<<<nchF, 256, 0, stream>>>(cntF, ptrF, csumF, NBF);
    scan2<<<1, 256, 0, stream>>>(csumF, nchF);
    scan3<<<(NBF + 255) / 256, 256, 0, stream>>>(ptrF, csumF, NBF);
    scan1<<<nchR, 256, 0, stream>>>(cntR, ptrR, csumR, NBR);
    scan2<<<1, 256, 0, stream>>>(csumR, nchR);
    scan3<<<(NBR + 255) / 256, 256, 0, stream>>>(ptrR, csumR, NBR);
    set_sentinels<<<1, 64, 0, stream>>>(ptrF, ptrR);
    fill_kernel<<<g_edges, 256, 0, stream>>>(dst_fwd, src_fwd, ptrF, cntF, colF, N_CELL);
    fill_kernel<<<g_edges, 256, 0, stream>>>(dst_rev, src_rev, ptrR, cntR, colR, N_RID);

    // ---------------- layer 1 ----------------
    y_gemm<<<N_RID / 16, 256, 0, stream>>>(x_rid, Wt1f, nullptr, y, N_RID);
    cell_fused<<<N_CELL / 16, 256, 0, stream>>>(x_cell, y, ptrF, colF, Wt1f, b1f,
                                                nullptr, cell1);
    rid_fused<<<N_RID / 16, 256, 0, stream>>>(x_rid, x_cell, ptrR, colR, Wt1r, b1r,
                                              nullptr, nullptr, rid1);
    colsum<<<1024, 256, 0, stream>>>(cell1, sums + 0, N_CELL);
    colsum<<<1024, 256, 0, stream>>>(rid1, sums + 64, N_RID);
    finalize_mean<<<1, 64, 0, stream>>>(sums + 0, 1.0f / N_CELL);
    finalize_mean<<<1, 64, 0, stream>>>(sums + 64, 1.0f / N_RID);

    // ---------------- layer 2 ----------------
    y_gemm<<<N_RID / 16, 256, 0, stream>>>(rid1, Wt2f, sums + 64, y, N_RID);
    cell_fused<<<N_CELL / 16, 256, 0, stream>>>(cell1, y, ptrF, colF, Wt2f, b2f,
                                                sums + 0, out);
    rid_fused<<<N_RID / 16, 256, 0, stream>>>(rid1, cell1, ptrR, colR, Wt2r, b2r,
                                              sums + 64, sums + 0, rid2);
    colsum<<<1024, 256, 0, stream>>>(out, sums + 128, N_CELL);
    colsum<<<1024, 256, 0, stream>>>(rid2, sums + 192, N_RID);
    finalize_mean<<<1, 64, 0, stream>>>(sums + 128, 1.0f / N_CELL);
    finalize_mean<<<1, 64, 0, stream>>>(sums + 192, 1.0f / N_RID);

    final_combine<<<(N_CELL * D) / 256, 256, 0, stream>>>(out, rid2, sums + 128,
                                                          sums + 192);
}

// Round 6
// 629.751 us; speedup vs baseline: 1.9850x; 1.9850x over previous
//
#include <hip/hip_runtime.h>

#define N_RID  100000
#define N_CELL 400000
#define NCOLS  4
#define NE     100000
#define D      64
#define TOTE   (NCOLS * NE)          // 400000 edges per direction
#define TILE   64                    // rows per block

typedef __attribute__((ext_vector_type(8))) short bf16x8;
typedef __attribute__((ext_vector_type(4))) float f32x4;

__device__ inline unsigned short f2bf(float f) {
    unsigned int u = __float_as_uint(f);
    return (unsigned short)((u + 0x7FFF + ((u >> 16) & 1)) >> 16);
}
__device__ inline float bf2f(unsigned short b) {
    return __uint_as_float(((unsigned int)b) << 16);
}
__device__ inline unsigned long long pack4(unsigned short a, unsigned short b,
                                           unsigned short c, unsigned short d) {
    return (unsigned long long)a | ((unsigned long long)b << 16) |
           ((unsigned long long)c << 32) | ((unsigned long long)d << 48);
}
// byte offset within a [16 rows][128B] bf16 tile, XOR-swizzled
__device__ inline int swz(int row, int kbyte) {
    return row * 128 + (kbyte ^ ((row & 7) << 4));
}

// ================================================================ CSR build
__global__ void hist_kernel(const int* __restrict__ dst, int* __restrict__ cnt,
                            int ndst) {
    int t = blockIdx.x * 256 + threadIdx.x;
    if (t >= TOTE) return;
    int c = t / NE;
    atomicAdd(&cnt[c * ndst + dst[t]], 1);
}

__global__ void scan1(const int* __restrict__ in, int* __restrict__ out,
                      int* __restrict__ csum, int n) {
    __shared__ int lds[256];
    int base = blockIdx.x * 1024 + threadIdx.x * 4;
    int v0 = 0, v1 = 0, v2 = 0, v3 = 0;
    if (base + 0 < n) v0 = in[base + 0];
    if (base + 1 < n) v1 = in[base + 1];
    if (base + 2 < n) v2 = in[base + 2];
    if (base + 3 < n) v3 = in[base + 3];
    int tsum = v0 + v1 + v2 + v3;
    lds[threadIdx.x] = tsum;
    __syncthreads();
    for (int off = 1; off < 256; off <<= 1) {
        int x = (threadIdx.x >= off) ? lds[threadIdx.x - off] : 0;
        __syncthreads();
        lds[threadIdx.x] += x;
        __syncthreads();
    }
    int excl = lds[threadIdx.x] - tsum;
    if (base + 0 < n) out[base + 0] = excl;
    if (base + 1 < n) out[base + 1] = excl + v0;
    if (base + 2 < n) out[base + 2] = excl + v0 + v1;
    if (base + 3 < n) out[base + 3] = excl + v0 + v1 + v2;
    if (threadIdx.x == 255) csum[blockIdx.x] = lds[255];
}

__global__ void scan2(int* __restrict__ a, int m) {
    __shared__ int lds[256];
    int per = (m + 255) >> 8;
    int st = threadIdx.x * per;
    int s = 0;
    for (int i = 0; i < per; ++i) if (st + i < m) s += a[st + i];
    lds[threadIdx.x] = s;
    __syncthreads();
    for (int off = 1; off < 256; off <<= 1) {
        int x = (threadIdx.x >= off) ? lds[threadIdx.x - off] : 0;
        __syncthreads();
        lds[threadIdx.x] += x;
        __syncthreads();
    }
    int run = lds[threadIdx.x] - s;
    for (int i = 0; i < per; ++i) if (st + i < m) { int v = a[st + i]; a[st + i] = run; run += v; }
}

__global__ void scan3(int* __restrict__ out, const int* __restrict__ csum, int n) {
    int i = blockIdx.x * 256 + threadIdx.x;
    if (i < n) out[i] += csum[i >> 10];
}

__global__ void set_sentinels(int* __restrict__ pF, int* __restrict__ pR) {
    if (threadIdx.x == 0) {
        pF[NCOLS * N_CELL] = TOTE;
        pR[NCOLS * N_RID]  = TOTE;
    }
}

__global__ void fill_kernel(const int* __restrict__ dst, const int* __restrict__ src,
                            const int* __restrict__ ptr, int* __restrict__ cnt,
                            int* __restrict__ col, int ndst) {
    int t = blockIdx.x * 256 + threadIdx.x;
    if (t >= TOTE) return;
    int c = t / NE;
    int bin = c * ndst + dst[t];
    int old = atomicSub(&cnt[bin], 1);
    col[ptr[bin] + old - 1] = src[t];
}

// ---------------- W prep: Wt[c][j][k] = bf16(W[c][k][j]) for 4 weight sets
__global__ void prep_w(const float* __restrict__ Wa, const float* __restrict__ Wb,
                       const float* __restrict__ Wc, const float* __restrict__ Wd,
                       unsigned short* __restrict__ Ta, unsigned short* __restrict__ Tb,
                       unsigned short* __restrict__ Tc, unsigned short* __restrict__ Td) {
    int t = blockIdx.x * 256 + threadIdx.x;
    if (t >= NCOLS * D * D) return;
    int c = t >> 12, jk = t & 4095, j = jk >> 6, k = jk & 63;
    int s = (c * D + k) * D + j;
    Ta[t] = f2bf(Wa[s]);
    Tb[t] = f2bf(Wb[s]);
    Tc[t] = f2bf(Wc[s]);
    Td[t] = f2bf(Wd[s]);
}

// ============================ unified SAGE layer kernel ======================
// out[n] = bbar + 0.25 * sum_c sc_c(n) * ( (h_dst[n]-mu_d) + sum_e h_src[col_e]
//                                           - deg_c(n)*mu_s ) @ W_c
// 64 rows/block, 4 waves (wave = relation), 8-lane groups own 8 strided rows,
// gather accumulates in registers (no atomics), 4x 16-row MFMA subtiles.
__global__ void __launch_bounds__(256, 3) sage_fused(
        const float* __restrict__ h_dst, const float* __restrict__ h_src,
        const int* __restrict__ ptr, const int* __restrict__ col,
        const unsigned short* __restrict__ Wt, const float* __restrict__ bias,
        const float* __restrict__ mu_d, const float* __restrict__ mu_s,
        float* __restrict__ out, float* __restrict__ csum, int n_dst) {
    __shared__ unsigned short aHi[NCOLS][16 * D];   // 8 KB
    __shared__ unsigned short aLo[NCOLS][16 * D];   // 8 KB
    __shared__ float part[NCOLS][16 * 68];          // 17.4 KB
    __shared__ int pl[NCOLS][TILE + 1];             // 1 KB

    const int tid = threadIdx.x, c = tid >> 6, l = tid & 63;
    const int g = l >> 3, q = l & 7;                // group, lane-in-group
    const int row0 = blockIdx.x * TILE;

    // coalesced ptr prefetch (clamped for the rid tail tile; sentinel valid)
    for (int i = tid; i < NCOLS * (TILE + 1); i += 256) {
        int cc = i / (TILE + 1), r = i % (TILE + 1);
        pl[cc][r] = ptr[(size_t)cc * n_dst + min(row0 + r, n_dst)];
    }

    float4 mus0 = {0,0,0,0}, mus1 = {0,0,0,0};
    if (mu_s) { mus0 = ((const float4*)mu_s)[2 * q]; mus1 = ((const float4*)mu_s)[2 * q + 1]; }

    // init accumulators with self term: h_dst[row] - mu_d   (cols q*8 .. q*8+7)
    float4 a0[8], a1[8];
#pragma unroll
    for (int i = 0; i < 8; ++i) {
        int r = (i >> 1) * 16 + (i & 1) * 8 + g;            // owned tile row
        int re = min(row0 + r, n_dst - 1);
        const float4* hp = (const float4*)(h_dst + (size_t)re * D);
        float4 v0 = hp[2 * q], v1 = hp[2 * q + 1];
        if (mu_d) {
            float4 m0 = ((const float4*)mu_d)[2 * q], m1 = ((const float4*)mu_d)[2 * q + 1];
            v0.x -= m0.x; v0.y -= m0.y; v0.z -= m0.z; v0.w -= m0.w;
            v1.x -= m1.x; v1.y -= m1.y; v1.z -= m1.z; v1.w -= m1.w;
        }
        a0[i] = v0; a1[i] = v1;
    }
    __syncthreads();   // pl ready

    // gather: each group walks its own rows' edge lists (8 groups issue in parallel)
#pragma unroll
    for (int i = 0; i < 8; ++i) {
        int r = (i >> 1) * 16 + (i & 1) * 8 + g;
        int p0 = pl[c][r], p1 = pl[c][r + 1];
        for (int e = p0; e < p1; ++e) {
            int v = col[e];
            const float4* sp = (const float4*)(h_src + (size_t)v * D);
            float4 s0 = sp[2 * q], s1 = sp[2 * q + 1];
            a0[i].x += s0.x; a0[i].y += s0.y; a0[i].z += s0.z; a0[i].w += s0.w;
            a1[i].x += s1.x; a1[i].y += s1.y; a1[i].z += s1.z; a1[i].w += s1.w;
        }
        float dg = (float)(p1 - p0);
        a0[i].x -= dg * mus0.x; a0[i].y -= dg * mus0.y;
        a0[i].z -= dg * mus0.z; a0[i].w -= dg * mus0.w;
        a1[i].x -= dg * mus1.x; a1[i].y -= dg * mus1.y;
        a1[i].z -= dg * mus1.z; a1[i].w -= dg * mus1.w;
    }

    // W fragments (relation c), loaded after gather to limit live VGPRs
    bf16x8 bfr[4][2];
#pragma unroll
    for (int nt = 0; nt < 4; ++nt)
#pragma unroll
        for (int kh = 0; kh < 2; ++kh)
            bfr[nt][kh] = *(const bf16x8*)(Wt +
                ((c * D + nt * 16 + (l & 15)) * D + kh * 32 + (l >> 4) * 8));

    float bb;
    { int j = tid & 63; bb = 0.25f * (bias[j] + bias[64 + j] + bias[128 + j] + bias[192 + j]); }
    float cs = 0.f;   // column-sum partial for column tid&63

#pragma unroll
    for (int s = 0; s < 4; ++s) {
        // A-build: rows s*16..s*16+15 of this wave's relation (hi/lo bf16, swizzled)
#pragma unroll
        for (int half = 0; half < 2; ++half) {
            float4 v0 = a0[2 * s + half], v1 = a1[2 * s + half];
            int rloc = half * 8 + g;
            unsigned short h0 = f2bf(v0.x), h1 = f2bf(v0.y), h2 = f2bf(v0.z), h3 = f2bf(v0.w);
            unsigned short h4 = f2bf(v1.x), h5 = f2bf(v1.y), h6 = f2bf(v1.z), h7 = f2bf(v1.w);
            unsigned short e0 = f2bf(v0.x - bf2f(h0)), e1 = f2bf(v0.y - bf2f(h1));
            unsigned short e2 = f2bf(v0.z - bf2f(h2)), e3 = f2bf(v0.w - bf2f(h3));
            unsigned short e4 = f2bf(v1.x - bf2f(h4)), e5 = f2bf(v1.y - bf2f(h5));
            unsigned short e6 = f2bf(v1.z - bf2f(h6)), e7 = f2bf(v1.w - bf2f(h7));
            int off = swz(rloc, q * 16);
            *(unsigned long long*)((char*)aHi[c] + off)     = pack4(h0, h1, h2, h3);
            *(unsigned long long*)((char*)aHi[c] + off + 8) = pack4(h4, h5, h6, h7);
            *(unsigned long long*)((char*)aLo[c] + off)     = pack4(e0, e1, e2, e3);
            *(unsigned long long*)((char*)aLo[c] + off + 8) = pack4(e4, e5, e6, e7);
        }
        // wave-local LDS RAW: compiler inserts lgkmcnt; no barrier needed
        bf16x8 ah[2], al[2];
#pragma unroll
        for (int kh = 0; kh < 2; ++kh) {
            int off = swz(l & 15, kh * 64 + (l >> 4) * 16);
            ah[kh] = *(const bf16x8*)((const char*)aHi[c] + off);
            al[kh] = *(const bf16x8*)((const char*)aLo[c] + off);
        }
        f32x4 macc[4] = {};
#pragma unroll
        for (int nt = 0; nt < 4; ++nt) {
            macc[nt] = __builtin_amdgcn_mfma_f32_16x16x32_bf16(ah[0], bfr[nt][0], macc[nt], 0, 0, 0);
            macc[nt] = __builtin_amdgcn_mfma_f32_16x16x32_bf16(ah[1], bfr[nt][1], macc[nt], 0, 0, 0);
            macc[nt] = __builtin_amdgcn_mfma_f32_16x16x32_bf16(al[0], bfr[nt][0], macc[nt], 0, 0, 0);
            macc[nt] = __builtin_amdgcn_mfma_f32_16x16x32_bf16(al[1], bfr[nt][1], macc[nt], 0, 0, 0);
        }
        // scale by sc = 1/(deg+1) and stage per-relation result
#pragma unroll
        for (int nt = 0; nt < 4; ++nt)
#pragma unroll
            for (int qq = 0; qq < 4; ++qq) {
                int rl = (l >> 4) * 4 + qq;
                int row = s * 16 + rl;
                float scv = 1.0f / (float)(pl[c][row + 1] - pl[c][row] + 1);
                part[c][rl * 68 + nt * 16 + (l & 15)] = scv * macc[nt][qq];
            }
        __syncthreads();
        // cross-relation mean + bias + store + colsum partial
        for (int i2 = tid; i2 < 16 * 64; i2 += 256) {
            int rl = i2 >> 6, j = i2 & 63;
            int grow = row0 + s * 16 + rl;
            float v = 0.25f * (part[0][rl * 68 + j] + part[1][rl * 68 + j] +
                               part[2][rl * 68 + j] + part[3][rl * 68 + j]) + bb;
            if (grow < n_dst) { out[(size_t)grow * D + j] = v; cs += v; }
        }
        __syncthreads();
    }

    // block-level column sum -> 16-replica global accumulator
    ((float*)part)[tid] = cs;
    __syncthreads();
    if (tid < 64) {
        const float* pp = (const float*)part;
        float s4 = pp[tid] + pp[tid + 64] + pp[tid + 128] + pp[tid + 192];
        atomicAdd(&csum[(blockIdx.x & 15) * 64 + tid], s4);
    }
}

// ----------------- reduce 16 replicas -> mean vector
__global__ void finalize16(const float* __restrict__ rep, float* __restrict__ mu,
                           float inv_n) {
    int j = threadIdx.x;   // 64 threads
    float s = 0.f;
    for (int k = 0; k < 16; ++k) s += rep[k * 64 + j];
    mu[j] = s * inv_n;
}

// ----------------- combine + center + relu (in place on out)
__global__ void final_combine(float* __restrict__ out, const float* __restrict__ rid,
        const float* __restrict__ mu_c, const float* __restrict__ mu_r) {
    int t = blockIdx.x * 256 + threadIdx.x;
    if (t >= N_CELL * D) return;
    int row = t >> 6, j = t & 63;
    float v = (row < N_RID) ? (rid[(size_t)row * D + j] - mu_r[j])
                            : (out[t] - mu_c[j]);
    out[t] = fmaxf(v, 0.0f);
}

extern "C" void kernel_launch(void* const* d_in, const int* in_sizes, int n_in,
                              void* d_out, int out_size, void* d_ws, size_t ws_size,
                              hipStream_t stream) {
    const float* x_rid  = (const float*)d_in[0];
    const float* x_cell = (const float*)d_in[1];
    const int* src_fwd  = (const int*)d_in[2];
    const int* dst_fwd  = (const int*)d_in[3];
    const int* src_rev  = (const int*)d_in[4];
    const int* dst_rev  = (const int*)d_in[5];
    const float* W1f = (const float*)d_in[6];
    const float* b1f = (const float*)d_in[7];
    const float* W1r = (const float*)d_in[8];
    const float* b1r = (const float*)d_in[9];
    const float* W2f = (const float*)d_in[10];
    const float* b2f = (const float*)d_in[11];
    const float* W2r = (const float*)d_in[12];
    const float* b2r = (const float*)d_in[13];
    float* out = (float*)d_out;

    float* ws    = (float*)d_ws;
    float* rid1  = ws;                                   //  6.4M f32
    float* cell1 = rid1  + (size_t)N_RID * D;            // 25.6M
    float* rid2  = cell1 + (size_t)N_CELL * D;           //  6.4M (build overlays)
    float* csums = rid2  + (size_t)N_RID * D;            //  4 x 1024
    float* mus   = csums + 4 * 1024;                     //  4 x 64
    int*   ptrF  = (int*)(mus + 4 * 64);
    int*   colF  = ptrF + (size_t)NCOLS * N_CELL + 1;
    int*   ptrR  = colF + TOTE;
    int*   colR  = ptrR + (size_t)NCOLS * N_RID + 1;
    uintptr_t wp = ((uintptr_t)(colR + TOTE) + 15) & ~(uintptr_t)15;
    unsigned short* Wt1f = (unsigned short*)wp;
    unsigned short* Wt1r = Wt1f + NCOLS * D * D;
    unsigned short* Wt2f = Wt1r + NCOLS * D * D;
    unsigned short* Wt2r = Wt2f + NCOLS * D * D;
    // build-phase overlays inside rid2 region (dead until layer 2)
    int*   cntF  = (int*)rid2;
    int*   cntR  = cntF + (size_t)NCOLS * N_CELL;
    int*   csumF = cntR + (size_t)NCOLS * N_RID;
    int*   csumR = csumF + 2048;

    float* cs_c1 = csums;              // layer1 cell colsum replicas
    float* cs_r1 = csums + 1024;
    float* cs_o  = csums + 2048;       // layer2 cell (out)
    float* cs_r2 = csums + 3072;
    float* mu_c1 = mus;
    float* mu_r1 = mus + 64;
    float* mu_o  = mus + 128;
    float* mu_r2 = mus + 192;

    const int NBF = NCOLS * N_CELL;
    const int NBR = NCOLS * N_RID;
    const int g_edges = (TOTE + 255) / 256;

    hipMemsetAsync(cntF, 0, (size_t)NBF * sizeof(int), stream);
    hipMemsetAsync(cntR, 0, (size_t)NBR * sizeof(int), stream);
    hipMemsetAsync(csums, 0, 4 * 1024 * sizeof(float), stream);

    prep_w<<<(NCOLS * D * D + 255) / 256, 256, 0, stream>>>(W1f, W1r, W2f, W2r,
                                                            Wt1f, Wt1r, Wt2f, Wt2r);

    hist_kernel<<<g_edges, 256, 0, stream>>>(dst_fwd, cntF, N_CELL);
    hist_kernel<<<g_edges, 256, 0, stream>>>(dst_rev, cntR, N_RID);
    int nchF = (NBF + 1023) / 1024, nchR = (NBR + 1023) / 1024;
    scan1<<<nchF, 256, 0, stream>>>(cntF, ptrF, csumF, NBF);
    scan2<<<1, 256, 0, stream>>>(csumF, nchF);
    scan3<<<(NBF + 255) / 256, 256, 0, stream>>>(ptrF, csumF, NBF);
    scan1<<<nchR, 256, 0, stream>>>(cntR, ptrR, csumR, NBR);
    scan2<<<1, 256, 0, stream>>>(csumR, nchR);
    scan3<<<(NBR + 255) / 256, 256, 0, stream>>>(ptrR, csumR, NBR);
    set_sentinels<<<1, 64, 0, stream>>>(ptrF, ptrR);
    fill_kernel<<<g_edges, 256, 0, stream>>>(dst_fwd, src_fwd, ptrF, cntF, colF, N_CELL);
    fill_kernel<<<g_edges, 256, 0, stream>>>(dst_rev, src_rev, ptrR, cntR, colR, N_RID);

    const int gC = N_CELL / TILE;                 // 6250
    const int gR = (N_RID + TILE - 1) / TILE;     // 1563

    // ---------------- layer 1 ----------------
    sage_fused<<<gC, 256, 0, stream>>>(x_cell, x_rid, ptrF, colF, Wt1f, b1f,
                                       nullptr, nullptr, cell1, cs_c1, N_CELL);
    sage_fused<<<gR, 256, 0, stream>>>(x_rid, x_cell, ptrR, colR, Wt1r, b1r,
                                       nullptr, nullptr, rid1, cs_r1, N_RID);
    finalize16<<<1, 64, 0, stream>>>(cs_c1, mu_c1, 1.0f / N_CELL);
    finalize16<<<1, 64, 0, stream>>>(cs_r1, mu_r1, 1.0f / N_RID);

    // ---------------- layer 2 ----------------
    sage_fused<<<gC, 256, 0, stream>>>(cell1, rid1, ptrF, colF, Wt2f, b2f,
                                       mu_c1, mu_r1, out, cs_o, N_CELL);
    sage_fused<<<gR, 256, 0, stream>>>(rid1, cell1, ptrR, colR, Wt2r, b2r,
                                       mu_r1, mu_c1, rid2, cs_r2, N_RID);
    finalize16<<<1, 64, 0, stream>>>(cs_o, mu_o, 1.0f / N_CELL);
    finalize16<<<1, 64, 0, stream>>>(cs_r2, mu_r2, 1.0f / N_RID);

    final_combine<<<(N_CELL * D) / 256, 256, 0, stream>>>(out, rid2, mu_o, mu_r2);
}

// Round 7
// 586.717 us; speedup vs baseline: 2.1306x; 1.0733x over previous
//
#include <hip/hip_runtime.h>

#define N_RID  100000
#define N_CELL 400000
#define NCOLS  4
#define NE     100000
#define D      64
#define TOTE   (NCOLS * NE)          // 400000 edges per direction
#define TILE   64                    // rows per block
#define ECAP   256                   // cached edges per relation per block

typedef __attribute__((ext_vector_type(8))) short bf16x8;
typedef __attribute__((ext_vector_type(4))) float f32x4;

__device__ inline unsigned short f2bf(float f) {
    unsigned int u = __float_as_uint(f);
    return (unsigned short)((u + 0x7FFF + ((u >> 16) & 1)) >> 16);
}
__device__ inline float bf2f(unsigned short b) {
    return __uint_as_float(((unsigned int)b) << 16);
}
__device__ inline unsigned long long pack4(unsigned short a, unsigned short b,
                                           unsigned short c, unsigned short d) {
    return (unsigned long long)a | ((unsigned long long)b << 16) |
           ((unsigned long long)c << 32) | ((unsigned long long)d << 48);
}
// byte offset within a [16 rows][128B] bf16 tile, XOR-swizzled
__device__ inline int swz(int row, int kbyte) {
    return row * 128 + (kbyte ^ ((row & 7) << 4));
}

// ================================================================ CSR build
__global__ void hist_kernel(const int* __restrict__ dst, int* __restrict__ cnt,
                            int ndst) {
    int t = blockIdx.x * 256 + threadIdx.x;
    if (t >= TOTE) return;
    int c = t / NE;
    atomicAdd(&cnt[c * ndst + dst[t]], 1);
}

__global__ void scan1(const int* __restrict__ in, int* __restrict__ out,
                      int* __restrict__ csum, int n) {
    __shared__ int lds[256];
    int base = blockIdx.x * 1024 + threadIdx.x * 4;
    int v0 = 0, v1 = 0, v2 = 0, v3 = 0;
    if (base + 0 < n) v0 = in[base + 0];
    if (base + 1 < n) v1 = in[base + 1];
    if (base + 2 < n) v2 = in[base + 2];
    if (base + 3 < n) v3 = in[base + 3];
    int tsum = v0 + v1 + v2 + v3;
    lds[threadIdx.x] = tsum;
    __syncthreads();
    for (int off = 1; off < 256; off <<= 1) {
        int x = (threadIdx.x >= off) ? lds[threadIdx.x - off] : 0;
        __syncthreads();
        lds[threadIdx.x] += x;
        __syncthreads();
    }
    int excl = lds[threadIdx.x] - tsum;
    if (base + 0 < n) out[base + 0] = excl;
    if (base + 1 < n) out[base + 1] = excl + v0;
    if (base + 2 < n) out[base + 2] = excl + v0 + v1;
    if (base + 3 < n) out[base + 3] = excl + v0 + v1 + v2;
    if (threadIdx.x == 255) csum[blockIdx.x] = lds[255];
}

__global__ void scan2(int* __restrict__ a, int m) {
    __shared__ int lds[256];
    int per = (m + 255) >> 8;
    int st = threadIdx.x * per;
    int s = 0;
    for (int i = 0; i < per; ++i) if (st + i < m) s += a[st + i];
    lds[threadIdx.x] = s;
    __syncthreads();
    for (int off = 1; off < 256; off <<= 1) {
        int x = (threadIdx.x >= off) ? lds[threadIdx.x - off] : 0;
        __syncthreads();
        lds[threadIdx.x] += x;
        __syncthreads();
    }
    int run = lds[threadIdx.x] - s;
    for (int i = 0; i < per; ++i) if (st + i < m) { int v = a[st + i]; a[st + i] = run; run += v; }
}

__global__ void scan3(int* __restrict__ out, const int* __restrict__ csum, int n) {
    int i = blockIdx.x * 256 + threadIdx.x;
    if (i < n) out[i] += csum[i >> 10];
}

__global__ void set_sentinels(int* __restrict__ pF, int* __restrict__ pR) {
    if (threadIdx.x == 0) {
        pF[NCOLS * N_CELL] = TOTE;
        pR[NCOLS * N_RID]  = TOTE;
    }
}

__global__ void fill_kernel(const int* __restrict__ dst, const int* __restrict__ src,
                            const int* __restrict__ ptr, int* __restrict__ cnt,
                            int* __restrict__ col, int ndst) {
    int t = blockIdx.x * 256 + threadIdx.x;
    if (t >= TOTE) return;
    int c = t / NE;
    int bin = c * ndst + dst[t];
    int old = atomicSub(&cnt[bin], 1);
    col[ptr[bin] + old - 1] = src[t];
}

// ---------------- W prep: Wt[c][j][k] = bf16(W[c][k][j]) for 4 weight sets
__global__ void prep_w(const float* __restrict__ Wa, const float* __restrict__ Wb,
                       const float* __restrict__ Wc, const float* __restrict__ Wd,
                       unsigned short* __restrict__ Ta, unsigned short* __restrict__ Tb,
                       unsigned short* __restrict__ Tc, unsigned short* __restrict__ Td) {
    int t = blockIdx.x * 256 + threadIdx.x;
    if (t >= NCOLS * D * D) return;
    int c = t >> 12, jk = t & 4095, j = jk >> 6, k = jk & 63;
    int s = (c * D + k) * D + j;
    Ta[t] = f2bf(Wa[s]);
    Tb[t] = f2bf(Wb[s]);
    Tc[t] = f2bf(Wc[s]);
    Td[t] = f2bf(Wd[s]);
}

// ============================ unified SAGE layer kernel ======================
// Wave w owns rows [w*16, w*16+16) of the block tile for ALL 4 relations
// (relations iterate sequentially). Per relation, the gathered+self A-tile is
// pre-scaled by sc_c = 1/(deg_c+1) so all relations accumulate into ONE MFMA
// accumulator (16 VGPR). No barriers in the main loop; waves run free.
__global__ void __launch_bounds__(256, 4) sage_fused(
        const float* __restrict__ h_dst, const float* __restrict__ h_src,
        const int* __restrict__ ptr, const int* __restrict__ col,
        const unsigned short* __restrict__ Wt, const float* __restrict__ bias,
        const float* __restrict__ mu_d, const float* __restrict__ mu_s,
        float* __restrict__ out, float* __restrict__ csum, int n_dst) {
    __shared__ int pl[NCOLS][TILE + 1];              // 1 KB
    __shared__ int ecol[NCOLS][ECAP];                // 4 KB
    __shared__ unsigned short aHi[4][16 * D];        // 8 KB (per-wave 2 KB)
    __shared__ unsigned short aLo[4][16 * D];        // 8 KB

    const int tid = threadIdx.x, w = tid >> 6, l = tid & 63;
    const int g = l >> 3, q = l & 7;                 // 8-lane group, lane-in-group
    const int row0 = blockIdx.x * TILE;

    // coalesced ptr prefetch (clamped; sentinel entry valid)
    for (int i = tid; i < NCOLS * (TILE + 1); i += 256) {
        int cc = i / (TILE + 1), r = i % (TILE + 1);
        pl[cc][r] = ptr[(size_t)cc * n_dst + min(row0 + r, n_dst)];
    }
    __syncthreads();

    // block-cooperative edge-list cache (coalesced; global fallback past ECAP)
#pragma unroll
    for (int c2 = 0; c2 < NCOLS; ++c2) {
        int eb = pl[c2][0];
        int ec = min(pl[c2][TILE] - eb, ECAP);
        for (int e = tid; e < ec; e += 256) ecol[c2][e] = col[eb + e];
    }

    // self term for the wave's 2 owned rows per group (centered by mu_d)
    float4 s0[2], s1[2];
#pragma unroll
    for (int i = 0; i < 2; ++i) {
        int re = min(row0 + w * 16 + i * 8 + g, n_dst - 1);
        const float4* hp = (const float4*)(h_dst + (size_t)re * D);
        float4 v0 = hp[2 * q], v1 = hp[2 * q + 1];
        if (mu_d) {
            float4 m0 = ((const float4*)mu_d)[2 * q], m1 = ((const float4*)mu_d)[2 * q + 1];
            v0.x -= m0.x; v0.y -= m0.y; v0.z -= m0.z; v0.w -= m0.w;
            v1.x -= m1.x; v1.y -= m1.y; v1.z -= m1.z; v1.w -= m1.w;
        }
        s0[i] = v0; s1[i] = v1;
    }
    float4 ms0 = {0, 0, 0, 0}, ms1 = {0, 0, 0, 0};
    if (mu_s) { ms0 = ((const float4*)mu_s)[2 * q]; ms1 = ((const float4*)mu_s)[2 * q + 1]; }
    __syncthreads();   // ecol ready; last barrier

    f32x4 macc[4] = {};
#pragma unroll
    for (int c = 0; c < NCOLS; ++c) {
        int eb = pl[c][0];
        // gather + pre-scale + A-build for this wave's 16-row tile
#pragma unroll
        for (int i = 0; i < 2; ++i) {
            int rloc = i * 8 + g;
            int grow = w * 16 + rloc;
            int p0 = pl[c][grow], p1 = pl[c][grow + 1];
            float4 t0 = s0[i], t1 = s1[i];
            for (int e = p0; e < p1; ++e) {
                int rel = e - eb;
                int v;
                if (rel < ECAP) v = ecol[c][rel];
                else            v = col[e];
                const float4* sp = (const float4*)(h_src + (size_t)v * D);
                float4 u0 = sp[2 * q], u1 = sp[2 * q + 1];
                t0.x += u0.x; t0.y += u0.y; t0.z += u0.z; t0.w += u0.w;
                t1.x += u1.x; t1.y += u1.y; t1.z += u1.z; t1.w += u1.w;
            }
            float dg = (float)(p1 - p0);
            t0.x -= dg * ms0.x; t0.y -= dg * ms0.y; t0.z -= dg * ms0.z; t0.w -= dg * ms0.w;
            t1.x -= dg * ms1.x; t1.y -= dg * ms1.y; t1.z -= dg * ms1.z; t1.w -= dg * ms1.w;
            float scv = 1.0f / (dg + 1.0f);
            t0.x *= scv; t0.y *= scv; t0.z *= scv; t0.w *= scv;
            t1.x *= scv; t1.y *= scv; t1.z *= scv; t1.w *= scv;
            unsigned short h0 = f2bf(t0.x), h1 = f2bf(t0.y), h2 = f2bf(t0.z), h3 = f2bf(t0.w);
            unsigned short h4 = f2bf(t1.x), h5 = f2bf(t1.y), h6 = f2bf(t1.z), h7 = f2bf(t1.w);
            unsigned short e0 = f2bf(t0.x - bf2f(h0)), e1 = f2bf(t0.y - bf2f(h1));
            unsigned short e2 = f2bf(t0.z - bf2f(h2)), e3 = f2bf(t0.w - bf2f(h3));
            unsigned short e4 = f2bf(t1.x - bf2f(h4)), e5 = f2bf(t1.y - bf2f(h5));
            unsigned short e6 = f2bf(t1.z - bf2f(h6)), e7 = f2bf(t1.w - bf2f(h7));
            int off = swz(rloc, q * 16);
            *(unsigned long long*)((char*)aHi[w] + off)     = pack4(h0, h1, h2, h3);
            *(unsigned long long*)((char*)aHi[w] + off + 8) = pack4(h4, h5, h6, h7);
            *(unsigned long long*)((char*)aLo[w] + off)     = pack4(e0, e1, e2, e3);
            *(unsigned long long*)((char*)aLo[w] + off + 8) = pack4(e4, e5, e6, e7);
        }
        // wave-local LDS RAW (compiler inserts lgkmcnt)
        bf16x8 ah[2], al[2];
#pragma unroll
        for (int kh = 0; kh < 2; ++kh) {
            int off = swz(l & 15, kh * 64 + (l >> 4) * 16);
            ah[kh] = *(const bf16x8*)((const char*)aHi[w] + off);
            al[kh] = *(const bf16x8*)((const char*)aLo[w] + off);
        }
        // JIT W fragments (L1/L2-resident 32 KB set) + MFMA accumulate
#pragma unroll
        for (int nt = 0; nt < 4; ++nt) {
            const unsigned short* wb = Wt + ((c * D + nt * 16 + (l & 15)) * D + (l >> 4) * 8);
            bf16x8 w0 = *(const bf16x8*)(wb);
            bf16x8 w1 = *(const bf16x8*)(wb + 32);
            macc[nt] = __builtin_amdgcn_mfma_f32_16x16x32_bf16(ah[0], w0, macc[nt], 0, 0, 0);
            macc[nt] = __builtin_amdgcn_mfma_f32_16x16x32_bf16(ah[1], w1, macc[nt], 0, 0, 0);
            macc[nt] = __builtin_amdgcn_mfma_f32_16x16x32_bf16(al[0], w0, macc[nt], 0, 0, 0);
            macc[nt] = __builtin_amdgcn_mfma_f32_16x16x32_bf16(al[1], w1, macc[nt], 0, 0, 0);
        }
    }

    // epilogue: wave-local store + fused column-sum
    const int j0 = l & 15;
    float bbv[4];
#pragma unroll
    for (int nt = 0; nt < 4; ++nt)
        bbv[nt] = 0.25f * (bias[nt * 16 + j0] + bias[64 + nt * 16 + j0] +
                           bias[128 + nt * 16 + j0] + bias[192 + nt * 16 + j0]);
    float cs[4] = {0.f, 0.f, 0.f, 0.f};
#pragma unroll
    for (int nt = 0; nt < 4; ++nt)
#pragma unroll
        for (int qq = 0; qq < 4; ++qq) {
            int grow = row0 + w * 16 + (l >> 4) * 4 + qq;
            if (grow < n_dst) {
                float v = 0.25f * macc[nt][qq] + bbv[nt];
                out[(size_t)grow * D + nt * 16 + j0] = v;
                cs[nt] += v;
            }
        }
#pragma unroll
    for (int nt = 0; nt < 4; ++nt) {
        float v = cs[nt];
        v += __shfl_xor(v, 16);
        v += __shfl_xor(v, 32);
        if (l < 16) atomicAdd(&csum[(blockIdx.x & 15) * 64 + nt * 16 + l], v);
    }
}

// ----------------- reduce 16 replicas -> mean vector
__global__ void finalize16(const float* __restrict__ rep, float* __restrict__ mu,
                           float inv_n) {
    int j = threadIdx.x;   // 64 threads
    float s = 0.f;
    for (int k = 0; k < 16; ++k) s += rep[k * 64 + j];
    mu[j] = s * inv_n;
}

// ----------------- combine + center + relu (in place on out)
__global__ void final_combine(float* __restrict__ out, const float* __restrict__ rid,
        const float* __restrict__ mu_c, const float* __restrict__ mu_r) {
    int t = blockIdx.x * 256 + threadIdx.x;
    if (t >= N_CELL * D) return;
    int row = t >> 6, j = t & 63;
    float v = (row < N_RID) ? (rid[(size_t)row * D + j] - mu_r[j])
                            : (out[t] - mu_c[j]);
    out[t] = fmaxf(v, 0.0f);
}

extern "C" void kernel_launch(void* const* d_in, const int* in_sizes, int n_in,
                              void* d_out, int out_size, void* d_ws, size_t ws_size,
                              hipStream_t stream) {
    const float* x_rid  = (const float*)d_in[0];
    const float* x_cell = (const float*)d_in[1];
    const int* src_fwd  = (const int*)d_in[2];
    const int* dst_fwd  = (const int*)d_in[3];
    const int* src_rev  = (const int*)d_in[4];
    const int* dst_rev  = (const int*)d_in[5];
    const float* W1f = (const float*)d_in[6];
    const float* b1f = (const float*)d_in[7];
    const float* W1r = (const float*)d_in[8];
    const float* b1r = (const float*)d_in[9];
    const float* W2f = (const float*)d_in[10];
    const float* b2f = (const float*)d_in[11];
    const float* W2r = (const float*)d_in[12];
    const float* b2r = (const float*)d_in[13];
    float* out = (float*)d_out;

    float* ws    = (float*)d_ws;
    float* rid1  = ws;                                   //  6.4M f32
    float* cell1 = rid1  + (size_t)N_RID * D;            // 25.6M
    float* rid2  = cell1 + (size_t)N_CELL * D;           //  6.4M (build overlays)
    float* csums = rid2  + (size_t)N_RID * D;            //  4 x 1024
    float* mus   = csums + 4 * 1024;                     //  4 x 64
    int*   ptrF  = (int*)(mus + 4 * 64);
    int*   colF  = ptrF + (size_t)NCOLS * N_CELL + 1;
    int*   ptrR  = colF + TOTE;
    int*   colR  = ptrR + (size_t)NCOLS * N_RID + 1;
    uintptr_t wp = ((uintptr_t)(colR + TOTE) + 15) & ~(uintptr_t)15;
    unsigned short* Wt1f = (unsigned short*)wp;
    unsigned short* Wt1r = Wt1f + NCOLS * D * D;
    unsigned short* Wt2f = Wt1r + NCOLS * D * D;
    unsigned short* Wt2r = Wt2f + NCOLS * D * D;
    // build-phase overlays inside rid2 region (dead until layer 2)
    int*   cntF  = (int*)rid2;
    int*   cntR  = cntF + (size_t)NCOLS * N_CELL;
    int*   csumF = cntR + (size_t)NCOLS * N_RID;
    int*   csumR = csumF + 2048;

    float* cs_c1 = csums;
    float* cs_r1 = csums + 1024;
    float* cs_o  = csums + 2048;
    float* cs_r2 = csums + 3072;
    float* mu_c1 = mus;
    float* mu_r1 = mus + 64;
    float* mu_o  = mus + 128;
    float* mu_r2 = mus + 192;

    const int NBF = NCOLS * N_CELL;
    const int NBR = NCOLS * N_RID;
    const int g_edges = (TOTE + 255) / 256;

    hipMemsetAsync(cntF, 0, (size_t)NBF * sizeof(int), stream);
    hipMemsetAsync(cntR, 0, (size_t)NBR * sizeof(int), stream);
    hipMemsetAsync(csums, 0, 4 * 1024 * sizeof(float), stream);

    prep_w<<<(NCOLS * D * D + 255) / 256, 256, 0, stream>>>(W1f, W1r, W2f, W2r,
                                                            Wt1f, Wt1r, Wt2f, Wt2r);

    hist_kernel<<<g_edges, 256, 0, stream>>>(dst_fwd, cntF, N_CELL);
    hist_kernel<<<g_edges, 256, 0, stream>>>(dst_rev, cntR, N_RID);
    int nchF = (NBF + 1023) / 1024, nchR = (NBR + 1023) / 1024;
    scan1<<<nchF, 256, 0, stream>>>(cntF, ptrF, csumF, NBF);
    scan2<<<1, 256, 0, stream>>>(csumF, nchF);
    scan3<<<(NBF + 255) / 256, 256, 0, stream>>>(ptrF, csumF, NBF);
    scan1<<<nchR, 256, 0, stream>>>(cntR, ptrR, csumR, NBR);
    scan2<<<1, 256, 0, stream>>>(csumR, nchR);
    scan3<<<(NBR + 255) / 256, 256, 0, stream>>>(ptrR, csumR, NBR);
    set_sentinels<<<1, 64, 0, stream>>>(ptrF, ptrR);
    fill_kernel<<<g_edges, 256, 0, stream>>>(dst_fwd, src_fwd, ptrF, cntF, colF, N_CELL);
    fill_kernel<<<g_edges, 256, 0, stream>>>(dst_rev, src_rev, ptrR, cntR, colR, N_RID);

    const int gC = N_CELL / TILE;                 // 6250
    const int gR = (N_RID + TILE - 1) / TILE;     // 1563

    // ---------------- layer 1 ----------------
    sage_fused<<<gC, 256, 0, stream>>>(x_cell, x_rid, ptrF, colF, Wt1f, b1f,
                                       nullptr, nullptr, cell1, cs_c1, N_CELL);
    sage_fused<<<gR, 256, 0, stream>>>(x_rid, x_cell, ptrR, colR, Wt1r, b1r,
                                       nullptr, nullptr, rid1, cs_r1, N_RID);
    finalize16<<<1, 64, 0, stream>>>(cs_c1, mu_c1, 1.0f / N_CELL);
    finalize16<<<1, 64, 0, stream>>>(cs_r1, mu_r1, 1.0f / N_RID);

    // ---------------- layer 2 ----------------
    sage_fused<<<gC, 256, 0, stream>>>(cell1, rid1, ptrF, colF, Wt2f, b2f,
                                       mu_c1, mu_r1, out, cs_o, N_CELL);
    sage_fused<<<gR, 256, 0, stream>>>(rid1, cell1, ptrR, colR, Wt2r, b2r,
                                       mu_r1, mu_c1, rid2, cs_r2, N_RID);
    finalize16<<<1, 64, 0, stream>>>(cs_o, mu_o, 1.0f / N_CELL);
    finalize16<<<1, 64, 0, stream>>>(cs_r2, mu_r2, 1.0f / N_RID);

    final_combine<<<(N_CELL * D) / 256, 256, 0, stream>>>(out, rid2, mu_o, mu_r2);
}